// Round 1
// baseline (380.805 us; speedup 1.0000x reference)
//
#include <hip/hip_runtime.h>
#include <hip/hip_bf16.h>
#include <stdint.h>
#include <cmath>

typedef unsigned short u16;
typedef __attribute__((ext_vector_type(8))) short bf16x8;   // 8 bf16 = 4 VGPRs (MFMA A/B frag)
typedef __attribute__((ext_vector_type(4))) float f32x4;    // MFMA C/D frag

#define DEVI static __device__ __forceinline__

constexpr int S_LEN = 2048;
constexpr int NHEAD = 16;
constexpr int HDIM  = 64;
constexpr int HID   = 1024;
constexpr int MROWS = 4 * 2048;   // B*S = 8192

// ---------- helpers ----------
DEVI u16 f2bf(float x) {                       // RNE fp32 -> bf16
  union { float f; uint32_t u; } a; a.f = x;
  uint32_t r = a.u + 0x7fffu + ((a.u >> 16) & 1u);
  return (u16)(r >> 16);
}

DEVI void gload16(const void* g, void* l) {    // 16B global -> LDS direct (wave-uniform lds base + lane*16)
  __builtin_amdgcn_global_load_lds((const __attribute__((address_space(1))) void*)g,
                                   (__attribute__((address_space(3))) void*)l, 16, 0, 0);
}

// ---------- fp32 -> bf16 convert ----------
__global__ void k_cvt(const float* __restrict__ src, u16* __restrict__ dst, int n4) {
  int stride = gridDim.x * blockDim.x;
  for (int i = blockIdx.x * blockDim.x + threadIdx.x; i < n4; i += stride) {
    float4 v = reinterpret_cast<const float4*>(src)[i];
    ushort4 o;
    o.x = f2bf(v.x); o.y = f2bf(v.y); o.z = f2bf(v.z); o.w = f2bf(v.w);
    reinterpret_cast<ushort4*>(dst)[i] = o;
  }
}

// ---------- shared 128x128 B^T GEMM mainloop (m97 structure) ----------
// C[M,N] = A[M,K] * B[N,K]^T, K = 1024, bf16 in, fp32 acc.
// 256 thr = 4 waves (2x2), wave tile 64x64 = 4x4 frags of 16x16, BK=32.
DEVI void gemm_ml(const u16* __restrict__ A, const u16* __restrict__ Bm,
                  int brow, int bcol, u16* As, u16* Bs, f32x4 acc[4][4]) {
  const int tid = threadIdx.x;
  const int wid = tid >> 6, lane = tid & 63;
  const int lr = lane & 15, lg = lane >> 4;
  const int wr = wid >> 1, wc = wid & 1;
  for (int kt = 0; kt < HID / 32; ++kt) {
    __syncthreads();                                  // prior iter LDS reads done
#pragma unroll
    for (int c = 0; c < 2; ++c) {
      int e = c * 2048 + tid * 8;                     // element index in [128][32] tile
      int row = e >> 5, kk = e & 31;
      gload16(A  + (size_t)(brow + row) * HID + kt * 32 + kk, As + c * 2048 + wid * 512);
      gload16(Bm + (size_t)(bcol + row) * HID + kt * 32 + kk, Bs + c * 2048 + wid * 512);
    }
    __syncthreads();                                  // vmcnt drained at barrier -> staged data visible
    bf16x8 af[4], bv[4];
#pragma unroll
    for (int m = 0; m < 4; ++m)
      af[m] = *reinterpret_cast<const bf16x8*>(As + (wr * 64 + m * 16 + lr) * 32 + lg * 8);
#pragma unroll
    for (int n = 0; n < 4; ++n)
      bv[n] = *reinterpret_cast<const bf16x8*>(Bs + (wc * 64 + n * 16 + lr) * 32 + lg * 8);
#pragma unroll
    for (int m = 0; m < 4; ++m)
#pragma unroll
      for (int n = 0; n < 4; ++n)
        acc[m][n] = __builtin_amdgcn_mfma_f32_16x16x32_bf16(af[m], bv[n], acc[m][n], 0, 0, 0);
  }
}

// ---------- QKV projection + fused RoPE, scatter to [B,NH,S,HD] bf16 ----------
__global__ __launch_bounds__(256) void k_gemm_qkv(const u16* __restrict__ X, const u16* __restrict__ W,
                                                  u16* __restrict__ Qb, u16* __restrict__ Kb,
                                                  u16* __restrict__ Vb) {
  __shared__ __align__(16) u16 As[128 * 32];
  __shared__ __align__(16) u16 Bs[128 * 32];
  f32x4 acc[4][4] = {};
  const int brow = blockIdx.x * 128, bcol = blockIdx.y * 128;
  gemm_ml(X, W, brow, bcol, As, Bs, acc);

  const int tid = threadIdx.x, wid = tid >> 6, lane = tid & 63;
  const int lr = lane & 15, lg = lane >> 4;
  const int wr = wid >> 1, wc = wid & 1;
  const int colbase = bcol + wc * 64;                 // wave covers exactly one head (64 cols, 64-aligned)
  const int mat = colbase >> 10;                      // 0=Q 1=K 2=V
  const int h = (colbase & 1023) >> 6;
  u16* dst = (mat == 0) ? Qb : ((mat == 1) ? Kb : Vb);
  const float qsc = (mat == 0) ? 0.125f : 1.0f;       // fold 1/sqrt(64) into Q

  if (mat < 2) {
    // angle(d) = t * base^(-(d&31)/32); n∈{0,2} share d&31=lr, n∈{1,3} share 16+lr
    const float L2B = 13.287712379549449f / 32.0f;    // log2(10000)/32
    const float inv0 = exp2f(-(float)lr * L2B);
    const float inv1 = exp2f(-(float)(16 + lr) * L2B);
#pragma unroll
    for (int m = 0; m < 4; ++m) {
#pragma unroll
      for (int r = 0; r < 4; ++r) {
        int grow = brow + wr * 64 + m * 16 + lg * 4 + r;
        int b = grow >> 11, s = grow & 2047;
        float s0, c0, s1, c1;
        __sincosf((float)s * inv0, &s0, &c0);
        __sincosf((float)s * inv1, &s1, &c1);
        float v0 = acc[m][0][r], v1 = acc[m][1][r], v2 = acc[m][2][r], v3 = acc[m][3][r];
        float r0 = (v0 * c0 - v2 * s0) * qsc;         // d<32: q*cos - q[d+32]*sin
        float r1 = (v1 * c1 - v3 * s1) * qsc;
        float r2 = (v2 * c0 + v0 * s0) * qsc;         // d>=32: q*cos + q[d-32]*sin
        float r3 = (v3 * c1 + v1 * s1) * qsc;
        size_t base = (((size_t)(b * NHEAD + h)) * S_LEN + s) * HDIM;
        dst[base + 0 * 16 + lr] = f2bf(r0);
        dst[base + 1 * 16 + lr] = f2bf(r1);
        dst[base + 2 * 16 + lr] = f2bf(r2);
        dst[base + 3 * 16 + lr] = f2bf(r3);
      }
    }
  } else {
#pragma unroll
    for (int m = 0; m < 4; ++m)
#pragma unroll
      for (int r = 0; r < 4; ++r) {
        int grow = brow + wr * 64 + m * 16 + lg * 4 + r;
        int b = grow >> 11, s = grow & 2047;
        size_t base = (((size_t)(b * NHEAD + h)) * S_LEN + s) * HDIM;
#pragma unroll
        for (int n = 0; n < 4; ++n)
          dst[base + n * 16 + lr] = f2bf(acc[m][n][r]);
      }
  }
}

// ---------- flash attention: one (b,h), 128 Q rows per block ----------
// 4 waves x 32 q-rows; KT=64; K swizzled LDS via pre-swizzled gload source;
// V reg-staged transposed into swizzled LDS; fp32 online softmax; P via padded LDS.
__global__ __launch_bounds__(256) void k_attn(const u16* __restrict__ Qb, const u16* __restrict__ Kb,
                                              const u16* __restrict__ Vb, u16* __restrict__ Ob) {
  __shared__ __align__(16) u16 Klds[64 * 64];         // [j][d] swizzled: byte ^= (j&7)<<4
  __shared__ __align__(16) u16 Vlds[64 * 64];         // [d][j] swizzled: byte ^= (d&7)<<4
  __shared__ __align__(16) u16 Plds[4][32 * 72];      // per-wave [32][64+8pad] (stride 144B = 9x16)
  const int qt = blockIdx.x, bh = blockIdx.y;
  const int tid = threadIdx.x, wid = tid >> 6, lane = tid & 63;
  const int lr = lane & 15, lg = lane >> 4;
  const u16* Qp = Qb + (size_t)bh * S_LEN * HDIM;
  const u16* Kp = Kb + (size_t)bh * S_LEN * HDIM;
  const u16* Vp = Vb + (size_t)bh * S_LEN * HDIM;

  // Q fragments: rows qt*128 + wid*32 + m*16 + lr, k = kk*32 + lg*8  (reused all 32 kv tiles)
  bf16x8 qf[2][2];
#pragma unroll
  for (int m = 0; m < 2; ++m)
#pragma unroll
    for (int kk = 0; kk < 2; ++kk) {
      int s = qt * 128 + wid * 32 + m * 16 + lr;
      qf[m][kk] = *reinterpret_cast<const bf16x8*>(Qp + (size_t)s * HDIM + kk * 32 + lg * 8);
    }

  f32x4 o[2][4] = {};
  float mrun[2][4], lrun[2][4];
#pragma unroll
  for (int m = 0; m < 2; ++m)
#pragma unroll
    for (int r = 0; r < 4; ++r) { mrun[m][r] = -INFINITY; lrun[m][r] = 0.f; }

  const int vd0 = (tid & 7) * 8;

  for (int kv0 = 0; kv0 < S_LEN; kv0 += 64) {
    __syncthreads();                                  // prior iter K/V LDS reads done
    // K tile: [64][64], row stride 128B; swizzle applied via global-source permutation (involution)
#pragma unroll
    for (int c = 0; c < 2; ++c) {
      int ob = c * 4096 + tid * 16;                   // dest byte in tile (linear)
      int row = ob >> 7;
      int src = ob ^ ((row & 7) << 4);
      gload16(Kp + (size_t)(kv0 + row) * HDIM + ((src & 127) >> 1),
              (u16*)((char*)Klds + c * 4096 + wid * 1024));
    }
    // V tile transposed: read V[j][d0..d0+7], write Vlds[d][j] (swizzled)
#pragma unroll
    for (int c2 = 0; c2 < 2; ++c2) {
      int j = c2 * 32 + (tid >> 3);
      bf16x8 vv = *reinterpret_cast<const bf16x8*>(Vp + (size_t)(kv0 + j) * HDIM + vd0);
#pragma unroll
      for (int dd = 0; dd < 8; ++dd) {
        int d = vd0 + dd;
        int byteoff = (d * 128 + j * 2) ^ ((d & 7) << 4);
        *(u16*)((char*)Vlds + byteoff) = (u16)vv[dd];
      }
    }
    __syncthreads();                                  // staging visible (vmcnt + lgkmcnt drained)

    // --- S = Q K^T (Q pre-scaled by 1/8) ---
    f32x4 sa[2][4] = {};
#pragma unroll
    for (int kk = 0; kk < 2; ++kk) {
      bf16x8 bk[4];
#pragma unroll
      for (int n = 0; n < 4; ++n) {
        int row = n * 16 + lr;
        int byteoff = (row * 128 + kk * 64 + lg * 16) ^ ((row & 7) << 4);
        bk[n] = *reinterpret_cast<const bf16x8*>((char*)Klds + byteoff);
      }
#pragma unroll
      for (int m = 0; m < 2; ++m)
#pragma unroll
        for (int n = 0; n < 4; ++n)
          sa[m][n] = __builtin_amdgcn_mfma_f32_16x16x32_bf16(qf[m][kk], bk[n], sa[m][n], 0, 0, 0);
    }

    // --- online softmax (row = m*16 + lg*4 + r; 16-lane shfl reduce over cols) ---
    float al[2][4], mnew[2][4];
#pragma unroll
    for (int m = 0; m < 2; ++m)
#pragma unroll
      for (int r = 0; r < 4; ++r) {
        float tm = fmaxf(fmaxf(sa[m][0][r], sa[m][1][r]), fmaxf(sa[m][2][r], sa[m][3][r]));
        tm = fmaxf(tm, __shfl_xor(tm, 1));
        tm = fmaxf(tm, __shfl_xor(tm, 2));
        tm = fmaxf(tm, __shfl_xor(tm, 4));
        tm = fmaxf(tm, __shfl_xor(tm, 8));
        float mn = fmaxf(mrun[m][r], tm);
        al[m][r] = __expf(mrun[m][r] - mn);
        mnew[m][r] = mn;
        mrun[m][r] = mn;
      }
#pragma unroll
    for (int m = 0; m < 2; ++m)
#pragma unroll
      for (int n = 0; n < 4; ++n)
#pragma unroll
        for (int r = 0; r < 4; ++r)
          sa[m][n][r] = __expf(sa[m][n][r] - mnew[m][r]);
#pragma unroll
    for (int m = 0; m < 2; ++m)
#pragma unroll
      for (int r = 0; r < 4; ++r) {
        float rs = sa[m][0][r] + sa[m][1][r] + sa[m][2][r] + sa[m][3][r];
        rs += __shfl_xor(rs, 1);
        rs += __shfl_xor(rs, 2);
        rs += __shfl_xor(rs, 4);
        rs += __shfl_xor(rs, 8);
        lrun[m][r] = lrun[m][r] * al[m][r] + rs;
      }
#pragma unroll
    for (int m = 0; m < 2; ++m)
#pragma unroll
      for (int n = 0; n < 4; ++n)
#pragma unroll
        for (int r = 0; r < 4; ++r)
          o[m][n][r] *= al[m][r];

    // --- P -> per-wave LDS (D-layout -> A-layout redistribution) ---
    u16* Pw = Plds[wid];
#pragma unroll
    for (int m = 0; m < 2; ++m)
#pragma unroll
      for (int n = 0; n < 4; ++n)
#pragma unroll
        for (int r = 0; r < 4; ++r) {
          int rowl = m * 16 + lg * 4 + r;
          Pw[rowl * 72 + n * 16 + lr] = f2bf(sa[m][n][r]);
        }
    asm volatile("s_waitcnt lgkmcnt(0)" ::: "memory");  // wave-private LDS: in-order DS + fence
    __builtin_amdgcn_sched_barrier(0);                  // rule #18: pin MFMA/ds_read below the wait

    // --- O += P V ---
#pragma unroll
    for (int kk = 0; kk < 2; ++kk) {
      bf16x8 pa[2], bv[4];
#pragma unroll
      for (int m = 0; m < 2; ++m)
        pa[m] = *reinterpret_cast<const bf16x8*>(Pw + (m * 16 + lr) * 72 + kk * 32 + lg * 8);
#pragma unroll
      for (int n = 0; n < 4; ++n) {
        int d = n * 16 + lr;
        int byteoff = (d * 128 + kk * 64 + lg * 16) ^ ((d & 7) << 4);
        bv[n] = *reinterpret_cast<const bf16x8*>((char*)Vlds + byteoff);
      }
#pragma unroll
      for (int m = 0; m < 2; ++m)
#pragma unroll
        for (int n = 0; n < 4; ++n)
          o[m][n] = __builtin_amdgcn_mfma_f32_16x16x32_bf16(pa[m], bv[n], o[m][n], 0, 0, 0);
    }
  }

  // epilogue: normalize, store [B,S,NH,HD] bf16 (= [M][1024] rows for out-proj)
  const int b = bh >> 4, h = bh & 15;
#pragma unroll
  for (int m = 0; m < 2; ++m)
#pragma unroll
    for (int n = 0; n < 4; ++n)
#pragma unroll
      for (int r = 0; r < 4; ++r) {
        int s = qt * 128 + wid * 32 + m * 16 + lg * 4 + r;
        int d = n * 16 + lr;
        float v = o[m][n][r] / lrun[m][r];
        Ob[(((size_t)b * S_LEN + s) * NHEAD + h) * HDIM + d] = f2bf(v);
      }
}

// ---------- output projection -> fp32 d_out ----------
__global__ __launch_bounds__(256) void k_gemm_out(const u16* __restrict__ Aa, const u16* __restrict__ Wo,
                                                  float* __restrict__ out) {
  __shared__ __align__(16) u16 As[128 * 32];
  __shared__ __align__(16) u16 Bs[128 * 32];
  f32x4 acc[4][4] = {};
  const int brow = blockIdx.x * 128, bcol = blockIdx.y * 128;
  gemm_ml(Aa, Wo, brow, bcol, As, Bs, acc);

  const int tid = threadIdx.x, wid = tid >> 6, lane = tid & 63;
  const int lr = lane & 15, lg = lane >> 4;
  const int wr = wid >> 1, wc = wid & 1;
#pragma unroll
  for (int m = 0; m < 4; ++m)
#pragma unroll
    for (int n = 0; n < 4; ++n)
#pragma unroll
      for (int r = 0; r < 4; ++r) {
        int grow = brow + wr * 64 + m * 16 + lg * 4 + r;
        int gcol = bcol + wc * 64 + n * 16 + lr;
        out[(size_t)grow * HID + gcol] = acc[m][n][r];
      }
}

// ---------- launcher ----------
extern "C" void kernel_launch(void* const* d_in, const int* in_sizes, int n_in,
                              void* d_out, int out_size, void* d_ws, size_t ws_size,
                              hipStream_t stream) {
  const float* hs = (const float*)d_in[0];
  const float* Wq = (const float*)d_in[1];
  const float* Wk = (const float*)d_in[2];
  const float* Wv = (const float*)d_in[3];
  const float* Wo = (const float*)d_in[4];

  char* ws = (char*)d_ws;
  u16* Xbf  = (u16*)(ws);                                   // 8192x1024      (16 MB)
  u16* Wqkv = (u16*)(ws + 16777216);                        // 3072x1024      ( 6 MB)
  u16* Wobf = (u16*)(ws + 23068672);                        // 1024x1024      ( 2 MB)
  u16* Qb   = (u16*)(ws + 25165824);                        // [B,NH,S,HD]    (16 MB)
  u16* Kb   = (u16*)(ws + 41943040);                        // [B,NH,S,HD]    (16 MB)
  u16* Vb   = (u16*)(ws + 58720256);                        // [B,NH,S,HD]    (16 MB)
  u16* AO   = (u16*)(ws + 75497472);                        // [B,S,NH,HD]    (16 MB) -> total 92274688 B

  k_cvt<<<2048, 256, 0, stream>>>(hs, Xbf, (MROWS * HID) / 4);
  k_cvt<<<1024, 256, 0, stream>>>(Wq, Wqkv,                 (HID * HID) / 4);
  k_cvt<<<1024, 256, 0, stream>>>(Wk, Wqkv + HID * HID,     (HID * HID) / 4);
  k_cvt<<<1024, 256, 0, stream>>>(Wv, Wqkv + 2 * HID * HID, (HID * HID) / 4);
  k_cvt<<<1024, 256, 0, stream>>>(Wo, Wobf,                 (HID * HID) / 4);

  k_gemm_qkv<<<dim3(MROWS / 128, 3072 / 128), 256, 0, stream>>>(Xbf, Wqkv, Qb, Kb, Vb);
  k_attn<<<dim3(S_LEN / 128, 4 * NHEAD), 256, 0, stream>>>(Qb, Kb, Vb, AO);
  k_gemm_out<<<dim3(MROWS / 128, HID / 128), 256, 0, stream>>>(AO, Wobf, (float*)d_out);
}

// Round 2
// 347.361 us; speedup vs baseline: 1.0963x; 1.0963x over previous
//
#include <hip/hip_runtime.h>
#include <hip/hip_bf16.h>
#include <stdint.h>
#include <cmath>

typedef unsigned short u16;
typedef __attribute__((ext_vector_type(8))) short bf16x8;   // 8 bf16 = 4 VGPRs (MFMA A/B frag)
typedef __attribute__((ext_vector_type(4))) float f32x4;    // MFMA C/D frag

#define DEVI static __device__ __forceinline__

constexpr int S_LEN = 2048;
constexpr int NHEAD = 16;
constexpr int HDIM  = 64;
constexpr int HID   = 1024;
constexpr int MROWS = 4 * 2048;   // B*S = 8192

// ---------- helpers ----------
DEVI u16 f2bf(float x) {                       // RNE fp32 -> bf16
  union { float f; uint32_t u; } a; a.f = x;
  uint32_t r = a.u + 0x7fffu + ((a.u >> 16) & 1u);
  return (u16)(r >> 16);
}

DEVI void gload16(const void* g, void* l) {    // 16B global -> LDS direct (wave-uniform lds base + lane*16)
  __builtin_amdgcn_global_load_lds((const __attribute__((address_space(1))) void*)g,
                                   (__attribute__((address_space(3))) void*)l, 16, 0, 0);
}

// ---------- fp32 -> bf16 convert ----------
__global__ void k_cvt(const float* __restrict__ src, u16* __restrict__ dst, int n4) {
  int stride = gridDim.x * blockDim.x;
  for (int i = blockIdx.x * blockDim.x + threadIdx.x; i < n4; i += stride) {
    float4 v = reinterpret_cast<const float4*>(src)[i];
    ushort4 o;
    o.x = f2bf(v.x); o.y = f2bf(v.y); o.z = f2bf(v.z); o.w = f2bf(v.w);
    reinterpret_cast<ushort4*>(dst)[i] = o;
  }
}

// ---------- shared 128x128 B^T GEMM mainloop (m97 structure) ----------
// C[M,N] = A[M,K] * B[N,K]^T, K = 1024, bf16 in, fp32 acc.
// 256 thr = 4 waves (2x2), wave tile 64x64 = 4x4 frags of 16x16, BK=32.
DEVI void gemm_ml(const u16* __restrict__ A, const u16* __restrict__ Bm,
                  int brow, int bcol, u16* As, u16* Bs, f32x4 acc[4][4]) {
  const int tid = threadIdx.x;
  const int wid = tid >> 6, lane = tid & 63;
  const int lr = lane & 15, lg = lane >> 4;
  const int wr = wid >> 1, wc = wid & 1;
  for (int kt = 0; kt < HID / 32; ++kt) {
    __syncthreads();                                  // prior iter LDS reads done
#pragma unroll
    for (int c = 0; c < 2; ++c) {
      int e = c * 2048 + tid * 8;                     // element index in [128][32] tile
      int row = e >> 5, kk = e & 31;
      gload16(A  + (size_t)(brow + row) * HID + kt * 32 + kk, As + c * 2048 + wid * 512);
      gload16(Bm + (size_t)(bcol + row) * HID + kt * 32 + kk, Bs + c * 2048 + wid * 512);
    }
    __syncthreads();                                  // vmcnt drained at barrier -> staged data visible
    bf16x8 af[4], bv[4];
#pragma unroll
    for (int m = 0; m < 4; ++m)
      af[m] = *reinterpret_cast<const bf16x8*>(As + (wr * 64 + m * 16 + lr) * 32 + lg * 8);
#pragma unroll
    for (int n = 0; n < 4; ++n)
      bv[n] = *reinterpret_cast<const bf16x8*>(Bs + (wc * 64 + n * 16 + lr) * 32 + lg * 8);
#pragma unroll
    for (int m = 0; m < 4; ++m)
#pragma unroll
      for (int n = 0; n < 4; ++n)
        acc[m][n] = __builtin_amdgcn_mfma_f32_16x16x32_bf16(af[m], bv[n], acc[m][n], 0, 0, 0);
  }
}

// ---------- QKV projection + fused RoPE, scatter to [B,NH,S,HD] bf16 ----------
__global__ __launch_bounds__(256) void k_gemm_qkv(const u16* __restrict__ X, const u16* __restrict__ W,
                                                  u16* __restrict__ Qb, u16* __restrict__ Kb,
                                                  u16* __restrict__ Vb) {
  __shared__ __align__(16) u16 As[128 * 32];
  __shared__ __align__(16) u16 Bs[128 * 32];
  f32x4 acc[4][4] = {};
  const int brow = blockIdx.x * 128, bcol = blockIdx.y * 128;
  gemm_ml(X, W, brow, bcol, As, Bs, acc);

  const int tid = threadIdx.x, wid = tid >> 6, lane = tid & 63;
  const int lr = lane & 15, lg = lane >> 4;
  const int wr = wid >> 1, wc = wid & 1;
  const int colbase = bcol + wc * 64;                 // wave covers exactly one head (64 cols, 64-aligned)
  const int mat = colbase >> 10;                      // 0=Q 1=K 2=V
  const int h = (colbase & 1023) >> 6;
  u16* dst = (mat == 0) ? Qb : ((mat == 1) ? Kb : Vb);
  const float qsc = (mat == 0) ? 0.125f : 1.0f;       // fold 1/sqrt(64) into Q

  if (mat < 2) {
    // angle(d) = t * base^(-(d&31)/32); n∈{0,2} share d&31=lr, n∈{1,3} share 16+lr
    const float L2B = 13.287712379549449f / 32.0f;    // log2(10000)/32
    const float inv0 = exp2f(-(float)lr * L2B);
    const float inv1 = exp2f(-(float)(16 + lr) * L2B);
#pragma unroll
    for (int m = 0; m < 4; ++m) {
#pragma unroll
      for (int r = 0; r < 4; ++r) {
        int grow = brow + wr * 64 + m * 16 + lg * 4 + r;
        int b = grow >> 11, s = grow & 2047;
        float s0, c0, s1, c1;
        __sincosf((float)s * inv0, &s0, &c0);
        __sincosf((float)s * inv1, &s1, &c1);
        float v0 = acc[m][0][r], v1 = acc[m][1][r], v2 = acc[m][2][r], v3 = acc[m][3][r];
        float r0 = (v0 * c0 - v2 * s0) * qsc;         // d<32: q*cos - q[d+32]*sin
        float r1 = (v1 * c1 - v3 * s1) * qsc;
        float r2 = (v2 * c0 + v0 * s0) * qsc;         // d>=32: q*cos + q[d-32]*sin
        float r3 = (v3 * c1 + v1 * s1) * qsc;
        size_t base = (((size_t)(b * NHEAD + h)) * S_LEN + s) * HDIM;
        dst[base + 0 * 16 + lr] = f2bf(r0);
        dst[base + 1 * 16 + lr] = f2bf(r1);
        dst[base + 2 * 16 + lr] = f2bf(r2);
        dst[base + 3 * 16 + lr] = f2bf(r3);
      }
    }
  } else {
#pragma unroll
    for (int m = 0; m < 4; ++m)
#pragma unroll
      for (int r = 0; r < 4; ++r) {
        int grow = brow + wr * 64 + m * 16 + lg * 4 + r;
        int b = grow >> 11, s = grow & 2047;
        size_t base = (((size_t)(b * NHEAD + h)) * S_LEN + s) * HDIM;
#pragma unroll
        for (int n = 0; n < 4; ++n)
          dst[base + n * 16 + lr] = f2bf(acc[m][n][r]);
      }
  }
}

// ---------- V transpose: [B,NH,S,HD] -> [B,NH,HD,S] (one-shot, ~32MB traffic) ----------
__global__ __launch_bounds__(256) void k_vt(const u16* __restrict__ Vb, u16* __restrict__ Vt) {
  __shared__ u16 t[64 * 65];                          // [d][s_local], +1 pad breaks conflicts
  const int st = blockIdx.x, bh = blockIdx.y;
  const int tid = threadIdx.x;
  const u16* src = Vb + ((size_t)bh * S_LEN + st * 64) * HDIM;
  u16* dst = Vt + (size_t)bh * HDIM * S_LEN + st * 64;
#pragma unroll
  for (int c = 0; c < 2; ++c) {
    int r = c * 32 + (tid >> 3), col = (tid & 7) * 8; // r = s_local, col = d
    bf16x8 v = *reinterpret_cast<const bf16x8*>(src + r * HDIM + col);
#pragma unroll
    for (int i = 0; i < 8; ++i) t[(col + i) * 65 + r] = (u16)v[i];
  }
  __syncthreads();
#pragma unroll
  for (int c = 0; c < 2; ++c) {
    int d = c * 32 + (tid >> 3), s0 = (tid & 7) * 8;
    bf16x8 v;
#pragma unroll
    for (int i = 0; i < 8; ++i) v[i] = (short)t[d * 65 + s0 + i];
    *reinterpret_cast<bf16x8*>(dst + (size_t)d * S_LEN + s0) = v;
  }
}

// ---------- flash attention: one (b,h), 128 Q rows per block ----------
// 4 waves x 32 q-rows; KT=64; K and V^T staged via gload16 with pre-swizzled
// global source (XOR (row&7)<<4); fp32 online softmax; P via swizzled per-wave LDS.
__global__ __launch_bounds__(256) void k_attn(const u16* __restrict__ Qb, const u16* __restrict__ Kb,
                                              const u16* __restrict__ Vt, const u16* __restrict__ Ob_dummy,
                                              u16* __restrict__ Ob) {
  __shared__ __align__(16) u16 Klds[64 * 64];         // [j][d] swizzled: byte ^= (j&7)<<4
  __shared__ __align__(16) u16 Vlds[64 * 64];         // [d][j] swizzled: byte ^= (d&7)<<4
  __shared__ __align__(16) u16 Plds[4][32 * 64];      // per-wave [32][64] swizzled: byte ^= (row&7)<<4
  const int qt = blockIdx.x, bh = blockIdx.y;
  const int tid = threadIdx.x, wid = tid >> 6, lane = tid & 63;
  const int lr = lane & 15, lg = lane >> 4;
  const u16* Qp = Qb + (size_t)bh * S_LEN * HDIM;
  const u16* Kp = Kb + (size_t)bh * S_LEN * HDIM;
  const u16* Vp = Vt + (size_t)bh * HDIM * S_LEN;     // [d][s]

  // Q fragments: rows qt*128 + wid*32 + m*16 + lr, k = kk*32 + lg*8  (reused all 32 kv tiles)
  bf16x8 qf[2][2];
#pragma unroll
  for (int m = 0; m < 2; ++m)
#pragma unroll
    for (int kk = 0; kk < 2; ++kk) {
      int s = qt * 128 + wid * 32 + m * 16 + lr;
      qf[m][kk] = *reinterpret_cast<const bf16x8*>(Qp + (size_t)s * HDIM + kk * 32 + lg * 8);
    }

  f32x4 o[2][4] = {};
  float mrun[2][4], lrun[2][4];
#pragma unroll
  for (int m = 0; m < 2; ++m)
#pragma unroll
    for (int r = 0; r < 4; ++r) { mrun[m][r] = -INFINITY; lrun[m][r] = 0.f; }

  for (int kv0 = 0; kv0 < S_LEN; kv0 += 64) {
    __syncthreads();                                  // prior iter K/V LDS reads done
    // K tile: [64 j][64 d]; V tile: [64 d][64 j]; swizzle via global-source permutation (involution)
#pragma unroll
    for (int c = 0; c < 2; ++c) {
      int ob = c * 4096 + tid * 16;                   // dest byte in tile (linear)
      int row = ob >> 7;
      int src = ob ^ ((row & 7) << 4);
      int colel = (src & 127) >> 1;
      gload16(Kp + (size_t)(kv0 + row) * HDIM + colel,
              (u16*)((char*)Klds + c * 4096 + wid * 1024));
      gload16(Vp + (size_t)row * S_LEN + kv0 + colel,
              (u16*)((char*)Vlds + c * 4096 + wid * 1024));
    }
    __syncthreads();                                  // staging visible (vmcnt drained at barrier)

    // --- S = Q K^T (Q pre-scaled by 1/8) ---
    f32x4 sa[2][4] = {};
#pragma unroll
    for (int kk = 0; kk < 2; ++kk) {
      bf16x8 bk[4];
#pragma unroll
      for (int n = 0; n < 4; ++n) {
        int row = n * 16 + lr;
        int byteoff = (row * 128 + kk * 64 + lg * 16) ^ ((row & 7) << 4);
        bk[n] = *reinterpret_cast<const bf16x8*>((char*)Klds + byteoff);
      }
#pragma unroll
      for (int m = 0; m < 2; ++m)
#pragma unroll
        for (int n = 0; n < 4; ++n)
          sa[m][n] = __builtin_amdgcn_mfma_f32_16x16x32_bf16(qf[m][kk], bk[n], sa[m][n], 0, 0, 0);
    }

    // --- online softmax (row = m*16 + lg*4 + r; 16-lane shfl reduce over cols) ---
    float al[2][4], mnew[2][4];
#pragma unroll
    for (int m = 0; m < 2; ++m)
#pragma unroll
      for (int r = 0; r < 4; ++r) {
        float tm = fmaxf(fmaxf(sa[m][0][r], sa[m][1][r]), fmaxf(sa[m][2][r], sa[m][3][r]));
        tm = fmaxf(tm, __shfl_xor(tm, 1));
        tm = fmaxf(tm, __shfl_xor(tm, 2));
        tm = fmaxf(tm, __shfl_xor(tm, 4));
        tm = fmaxf(tm, __shfl_xor(tm, 8));
        float mn = fmaxf(mrun[m][r], tm);
        al[m][r] = __expf(mrun[m][r] - mn);
        mnew[m][r] = mn;
        mrun[m][r] = mn;
      }
#pragma unroll
    for (int m = 0; m < 2; ++m)
#pragma unroll
      for (int n = 0; n < 4; ++n)
#pragma unroll
        for (int r = 0; r < 4; ++r)
          sa[m][n][r] = __expf(sa[m][n][r] - mnew[m][r]);
#pragma unroll
    for (int m = 0; m < 2; ++m)
#pragma unroll
      for (int r = 0; r < 4; ++r) {
        float rs = sa[m][0][r] + sa[m][1][r] + sa[m][2][r] + sa[m][3][r];
        rs += __shfl_xor(rs, 1);
        rs += __shfl_xor(rs, 2);
        rs += __shfl_xor(rs, 4);
        rs += __shfl_xor(rs, 8);
        lrun[m][r] = lrun[m][r] * al[m][r] + rs;
      }
#pragma unroll
    for (int m = 0; m < 2; ++m)
#pragma unroll
      for (int n = 0; n < 4; ++n)
#pragma unroll
        for (int r = 0; r < 4; ++r)
          o[m][n][r] *= al[m][r];

    // --- P -> per-wave swizzled LDS (D-layout -> A-layout redistribution) ---
    char* Pw = (char*)Plds[wid];
#pragma unroll
    for (int m = 0; m < 2; ++m)
#pragma unroll
      for (int n = 0; n < 4; ++n)
#pragma unroll
        for (int r = 0; r < 4; ++r) {
          int rowl = m * 16 + lg * 4 + r;
          int byteoff = (rowl * 128 + (n * 16 + lr) * 2) ^ ((rowl & 7) << 4);
          *(u16*)(Pw + byteoff) = f2bf(sa[m][n][r]);
        }
    asm volatile("s_waitcnt lgkmcnt(0)" ::: "memory");  // wave-private LDS: in-order DS + fence
    __builtin_amdgcn_sched_barrier(0);                  // rule #18: pin MFMA/ds_read below the wait

    // --- O += P V ---
#pragma unroll
    for (int kk = 0; kk < 2; ++kk) {
      bf16x8 pa[2], bv[4];
#pragma unroll
      for (int m = 0; m < 2; ++m) {
        int rowl = m * 16 + lr;
        int byteoff = (rowl * 128 + kk * 64 + lg * 16) ^ ((rowl & 7) << 4);
        pa[m] = *reinterpret_cast<const bf16x8*>(Pw + byteoff);
      }
#pragma unroll
      for (int n = 0; n < 4; ++n) {
        int d = n * 16 + lr;
        int byteoff = (d * 128 + kk * 64 + lg * 16) ^ ((d & 7) << 4);
        bv[n] = *reinterpret_cast<const bf16x8*>((char*)Vlds + byteoff);
      }
#pragma unroll
      for (int m = 0; m < 2; ++m)
#pragma unroll
        for (int n = 0; n < 4; ++n)
          o[m][n] = __builtin_amdgcn_mfma_f32_16x16x32_bf16(pa[m], bv[n], o[m][n], 0, 0, 0);
    }
  }

  // epilogue: normalize, store [B,S,NH,HD] bf16 (= [M][1024] rows for out-proj)
  const int b = bh >> 4, h = bh & 15;
#pragma unroll
  for (int m = 0; m < 2; ++m)
#pragma unroll
    for (int n = 0; n < 4; ++n)
#pragma unroll
      for (int r = 0; r < 4; ++r) {
        int s = qt * 128 + wid * 32 + m * 16 + lg * 4 + r;
        int d = n * 16 + lr;
        float v = o[m][n][r] / lrun[m][r];
        Ob[(((size_t)b * S_LEN + s) * NHEAD + h) * HDIM + d] = f2bf(v);
      }
}

// ---------- output projection -> fp32 d_out ----------
__global__ __launch_bounds__(256) void k_gemm_out(const u16* __restrict__ Aa, const u16* __restrict__ Wo,
                                                  float* __restrict__ out) {
  __shared__ __align__(16) u16 As[128 * 32];
  __shared__ __align__(16) u16 Bs[128 * 32];
  f32x4 acc[4][4] = {};
  const int brow = blockIdx.x * 128, bcol = blockIdx.y * 128;
  gemm_ml(Aa, Wo, brow, bcol, As, Bs, acc);

  const int tid = threadIdx.x, wid = tid >> 6, lane = tid & 63;
  const int lr = lane & 15, lg = lane >> 4;
  const int wr = wid >> 1, wc = wid & 1;
#pragma unroll
  for (int m = 0; m < 4; ++m)
#pragma unroll
    for (int n = 0; n < 4; ++n)
#pragma unroll
      for (int r = 0; r < 4; ++r) {
        int grow = brow + wr * 64 + m * 16 + lg * 4 + r;
        int gcol = bcol + wc * 64 + n * 16 + lr;
        out[(size_t)grow * HID + gcol] = acc[m][n][r];
      }
}

// ---------- launcher ----------
extern "C" void kernel_launch(void* const* d_in, const int* in_sizes, int n_in,
                              void* d_out, int out_size, void* d_ws, size_t ws_size,
                              hipStream_t stream) {
  const float* hs = (const float*)d_in[0];
  const float* Wq = (const float*)d_in[1];
  const float* Wk = (const float*)d_in[2];
  const float* Wv = (const float*)d_in[3];
  const float* Wo = (const float*)d_in[4];

  char* ws = (char*)d_ws;
  u16* Xbf  = (u16*)(ws);                                   // 8192x1024      (16 MB)
  u16* Wqkv = (u16*)(ws + 16777216);                        // 3072x1024      ( 6 MB)
  u16* Wobf = (u16*)(ws + 23068672);                        // 1024x1024      ( 2 MB)
  u16* Qb   = (u16*)(ws + 25165824);                        // [B,NH,S,HD]    (16 MB)
  u16* Kb   = (u16*)(ws + 41943040);                        // [B,NH,S,HD]    (16 MB)
  u16* Vb   = (u16*)(ws + 58720256);                        // [B,NH,S,HD]    (16 MB)
  u16* AO   = (u16*)(ws + 75497472);                        // [B,S,NH,HD]    (16 MB) -> total 92274688 B
  u16* Vt   = Xbf;                                          // [B,NH,HD,S]: reuse Xbf (dead after k_gemm_qkv)

  k_cvt<<<2048, 256, 0, stream>>>(hs, Xbf, (MROWS * HID) / 4);
  k_cvt<<<1024, 256, 0, stream>>>(Wq, Wqkv,                 (HID * HID) / 4);
  k_cvt<<<1024, 256, 0, stream>>>(Wk, Wqkv + HID * HID,     (HID * HID) / 4);
  k_cvt<<<1024, 256, 0, stream>>>(Wv, Wqkv + 2 * HID * HID, (HID * HID) / 4);
  k_cvt<<<1024, 256, 0, stream>>>(Wo, Wobf,                 (HID * HID) / 4);

  k_gemm_qkv<<<dim3(MROWS / 128, 3072 / 128), 256, 0, stream>>>(Xbf, Wqkv, Qb, Kb, Vb);
  k_vt<<<dim3(S_LEN / 64, 4 * NHEAD), 256, 0, stream>>>(Vb, Vt);
  k_attn<<<dim3(S_LEN / 128, 4 * NHEAD), 256, 0, stream>>>(Qb, Kb, Vt, nullptr, AO);
  k_gemm_out<<<dim3(MROWS / 128, HID / 128), 256, 0, stream>>>(AO, Wobf, (float*)d_out);
}

// Round 3
// 248.486 us; speedup vs baseline: 1.5325x; 1.3979x over previous
//
#include <hip/hip_runtime.h>
#include <hip/hip_bf16.h>
#include <stdint.h>
#include <cmath>

typedef unsigned short u16;
typedef __attribute__((ext_vector_type(8))) short bf16x8;   // 8 bf16 = 4 VGPRs (MFMA A/B frag)
typedef __attribute__((ext_vector_type(4))) float f32x4;    // MFMA C/D frag

#define DEVI static __device__ __forceinline__

constexpr int S_LEN = 2048;
constexpr int NHEAD = 16;
constexpr int HDIM  = 64;
constexpr int HID   = 1024;
constexpr int MROWS = 4 * 2048;   // B*S = 8192

// ---------- helpers ----------
DEVI u16 f2bf(float x) {                       // RNE fp32 -> bf16
  union { float f; uint32_t u; } a; a.f = x;
  uint32_t r = a.u + 0x7fffu + ((a.u >> 16) & 1u);
  return (u16)(r >> 16);
}

DEVI void gload16(const void* g, void* l) {    // 16B global -> LDS direct (wave-uniform lds base + lane*16)
  __builtin_amdgcn_global_load_lds((const __attribute__((address_space(1))) void*)g,
                                   (__attribute__((address_space(3))) void*)l, 16, 0, 0);
}

// ---------- fp32 -> bf16 convert ----------
__global__ void k_cvt(const float* __restrict__ src, u16* __restrict__ dst, int n4) {
  int stride = gridDim.x * blockDim.x;
  for (int i = blockIdx.x * blockDim.x + threadIdx.x; i < n4; i += stride) {
    float4 v = reinterpret_cast<const float4*>(src)[i];
    ushort4 o;
    o.x = f2bf(v.x); o.y = f2bf(v.y); o.z = f2bf(v.z); o.w = f2bf(v.w);
    reinterpret_cast<ushort4*>(dst)[i] = o;
  }
}

// all four 1024x1024 weights in one launch: Wq,Wk,Wv -> Wqkv (concat), Wo -> Wobf
__global__ void k_cvtw(const float* __restrict__ Wq, const float* __restrict__ Wk,
                       const float* __restrict__ Wv, const float* __restrict__ Wo,
                       u16* __restrict__ Wqkv, u16* __restrict__ Wobf) {
  constexpr int Q4 = (HID * HID) / 4;                 // float4s per matrix
  int i = blockIdx.x * blockDim.x + threadIdx.x;      // grid exactly covers 4*Q4
  int mat = i >> 18, loc = i & (Q4 - 1);              // Q4 = 2^18
  const float* src = (mat == 0) ? Wq : (mat == 1) ? Wk : (mat == 2) ? Wv : Wo;
  u16* dst = (mat < 3) ? (Wqkv + mat * HID * HID) : Wobf;
  float4 v = reinterpret_cast<const float4*>(src)[loc];
  ushort4 o;
  o.x = f2bf(v.x); o.y = f2bf(v.y); o.z = f2bf(v.z); o.w = f2bf(v.w);
  reinterpret_cast<ushort4*>(dst)[loc] = o;
}

// ---------- shared 128x128 B^T GEMM mainloop (m97 structure) ----------
DEVI void gemm_ml(const u16* __restrict__ A, const u16* __restrict__ Bm,
                  int brow, int bcol, u16* As, u16* Bs, f32x4 acc[4][4]) {
  const int tid = threadIdx.x;
  const int wid = tid >> 6, lane = tid & 63;
  const int lr = lane & 15, lg = lane >> 4;
  const int wr = wid >> 1, wc = wid & 1;
  for (int kt = 0; kt < HID / 32; ++kt) {
    __syncthreads();                                  // prior iter LDS reads done
#pragma unroll
    for (int c = 0; c < 2; ++c) {
      int e = c * 2048 + tid * 8;                     // element index in [128][32] tile
      int row = e >> 5, kk = e & 31;
      gload16(A  + (size_t)(brow + row) * HID + kt * 32 + kk, As + c * 2048 + wid * 512);
      gload16(Bm + (size_t)(bcol + row) * HID + kt * 32 + kk, Bs + c * 2048 + wid * 512);
    }
    __syncthreads();                                  // vmcnt drained at barrier -> staged data visible
    bf16x8 af[4], bv[4];
#pragma unroll
    for (int m = 0; m < 4; ++m)
      af[m] = *reinterpret_cast<const bf16x8*>(As + (wr * 64 + m * 16 + lr) * 32 + lg * 8);
#pragma unroll
    for (int n = 0; n < 4; ++n)
      bv[n] = *reinterpret_cast<const bf16x8*>(Bs + (wc * 64 + n * 16 + lr) * 32 + lg * 8);
#pragma unroll
    for (int m = 0; m < 4; ++m)
#pragma unroll
      for (int n = 0; n < 4; ++n)
        acc[m][n] = __builtin_amdgcn_mfma_f32_16x16x32_bf16(af[m], bv[n], acc[m][n], 0, 0, 0);
  }
}

// ---------- QKV projection + fused RoPE, scatter to [B,NH,S,HD] bf16 ----------
__global__ __launch_bounds__(256) void k_gemm_qkv(const u16* __restrict__ X, const u16* __restrict__ W,
                                                  u16* __restrict__ Qb, u16* __restrict__ Kb,
                                                  u16* __restrict__ Vb) {
  __shared__ __align__(16) u16 As[128 * 32];
  __shared__ __align__(16) u16 Bs[128 * 32];
  f32x4 acc[4][4] = {};
  const int brow = blockIdx.x * 128, bcol = blockIdx.y * 128;
  gemm_ml(X, W, brow, bcol, As, Bs, acc);

  const int tid = threadIdx.x, wid = tid >> 6, lane = tid & 63;
  const int lr = lane & 15, lg = lane >> 4;
  const int wr = wid >> 1, wc = wid & 1;
  const int colbase = bcol + wc * 64;                 // wave covers exactly one head (64 cols, 64-aligned)
  const int mat = colbase >> 10;                      // 0=Q 1=K 2=V
  const int h = (colbase & 1023) >> 6;
  u16* dst = (mat == 0) ? Qb : ((mat == 1) ? Kb : Vb);
  // Q: fold 1/sqrt(64) AND log2(e) (softmax runs in exp2 domain)
  const float qsc = (mat == 0) ? 0.125f * 1.4426950408889634f : 1.0f;

  if (mat < 2) {
    const float L2B = 13.287712379549449f / 32.0f;    // log2(10000)/32
    const float inv0 = exp2f(-(float)lr * L2B);
    const float inv1 = exp2f(-(float)(16 + lr) * L2B);
#pragma unroll
    for (int m = 0; m < 4; ++m) {
#pragma unroll
      for (int r = 0; r < 4; ++r) {
        int grow = brow + wr * 64 + m * 16 + lg * 4 + r;
        int b = grow >> 11, s = grow & 2047;
        float s0, c0, s1, c1;
        __sincosf((float)s * inv0, &s0, &c0);
        __sincosf((float)s * inv1, &s1, &c1);
        float v0 = acc[m][0][r], v1 = acc[m][1][r], v2 = acc[m][2][r], v3 = acc[m][3][r];
        float r0 = (v0 * c0 - v2 * s0) * qsc;         // d<32: q*cos - q[d+32]*sin
        float r1 = (v1 * c1 - v3 * s1) * qsc;
        float r2 = (v2 * c0 + v0 * s0) * qsc;         // d>=32: q*cos + q[d-32]*sin
        float r3 = (v3 * c1 + v1 * s1) * qsc;
        size_t base = (((size_t)(b * NHEAD + h)) * S_LEN + s) * HDIM;
        dst[base + 0 * 16 + lr] = f2bf(r0);
        dst[base + 1 * 16 + lr] = f2bf(r1);
        dst[base + 2 * 16 + lr] = f2bf(r2);
        dst[base + 3 * 16 + lr] = f2bf(r3);
      }
    }
  } else {
#pragma unroll
    for (int m = 0; m < 4; ++m)
#pragma unroll
      for (int r = 0; r < 4; ++r) {
        int grow = brow + wr * 64 + m * 16 + lg * 4 + r;
        int b = grow >> 11, s = grow & 2047;
        size_t base = (((size_t)(b * NHEAD + h)) * S_LEN + s) * HDIM;
#pragma unroll
        for (int n = 0; n < 4; ++n)
          dst[base + n * 16 + lr] = f2bf(acc[m][n][r]);
      }
  }
}

// ---------- V transpose: [B,NH,S,HD] -> [B,NH,HD,S] ----------
__global__ __launch_bounds__(256) void k_vt(const u16* __restrict__ Vb, u16* __restrict__ Vt) {
  __shared__ u16 t[64 * 65];
  const int st = blockIdx.x, bh = blockIdx.y;
  const int tid = threadIdx.x;
  const u16* src = Vb + ((size_t)bh * S_LEN + st * 64) * HDIM;
  u16* dst = Vt + (size_t)bh * HDIM * S_LEN + st * 64;
#pragma unroll
  for (int c = 0; c < 2; ++c) {
    int r = c * 32 + (tid >> 3), col = (tid & 7) * 8;
    bf16x8 v = *reinterpret_cast<const bf16x8*>(src + r * HDIM + col);
#pragma unroll
    for (int i = 0; i < 8; ++i) t[(col + i) * 65 + r] = (u16)v[i];
  }
  __syncthreads();
#pragma unroll
  for (int c = 0; c < 2; ++c) {
    int d = c * 32 + (tid >> 3), s0 = (tid & 7) * 8;
    bf16x8 v;
#pragma unroll
    for (int i = 0; i < 8; ++i) v[i] = (short)t[d * 65 + s0 + i];
    *reinterpret_cast<bf16x8*>(dst + (size_t)d * S_LEN + s0) = v;
  }
}

// ---------- flash attention, swapped-QK^T in-register softmax ----------
// 4 waves x 32 q-rows; KT=64. S^T = mfma(K_frag, Q_frag): lane holds 16 k-vals
// for q = nq*16 + (lane&15). Row reduce = 15 local + 2 shfl. P packed via
// v_cvt_pk_bf16_f32 into swizzled per-wave LDS (transpose in addressing).
__global__ __launch_bounds__(256) void k_attn(const u16* __restrict__ Qb, const u16* __restrict__ Kb,
                                              const u16* __restrict__ Vt, u16* __restrict__ Ob) {
  __shared__ __align__(16) u16 Klds[64 * 64];         // [j][d] swizzled: byte ^= (j&7)<<4
  __shared__ __align__(16) u16 Vlds[64 * 64];         // [d][j] swizzled: byte ^= (d&7)<<4
  __shared__ __align__(16) u16 Plds[4][32 * 64];      // per-wave [q32][k64] swizzled: byte ^= (q&7)<<4
  const int qt = blockIdx.x, bh = blockIdx.y;
  const int tid = threadIdx.x, wid = tid >> 6, lane = tid & 63;
  const int lr = lane & 15, lg = lane >> 4;
  const u16* Qp = Qb + (size_t)bh * S_LEN * HDIM;
  const u16* Kp = Kb + (size_t)bh * S_LEN * HDIM;
  const u16* Vp = Vt + (size_t)bh * HDIM * S_LEN;     // [d][s]

  // Q fragments (B-operand role): rows qt*128 + wid*32 + nq*16 + lr
  bf16x8 qf[2][2];
#pragma unroll
  for (int nq = 0; nq < 2; ++nq)
#pragma unroll
    for (int kk = 0; kk < 2; ++kk) {
      int s = qt * 128 + wid * 32 + nq * 16 + lr;
      qf[nq][kk] = *reinterpret_cast<const bf16x8*>(Qp + (size_t)s * HDIM + kk * 32 + lg * 8);
    }

  f32x4 o[2][4] = {};
  float mrun[2] = { -INFINITY, -INFINITY };
  float lrun[2] = { 0.f, 0.f };

  for (int kv0 = 0; kv0 < S_LEN; kv0 += 64) {
    __syncthreads();                                  // prior iter K/V/P LDS reads done
#pragma unroll
    for (int c = 0; c < 2; ++c) {
      int ob = c * 4096 + tid * 16;                   // dest byte in tile (linear)
      int row = ob >> 7;
      int src = ob ^ ((row & 7) << 4);
      int colel = (src & 127) >> 1;
      gload16(Kp + (size_t)(kv0 + row) * HDIM + colel,
              (u16*)((char*)Klds + c * 4096 + wid * 1024));
      gload16(Vp + (size_t)row * S_LEN + kv0 + colel,
              (u16*)((char*)Vlds + c * 4096 + wid * 1024));
    }
    __syncthreads();                                  // staging visible (vmcnt drained at barrier)

    // --- S^T = K Q^T (Q pre-scaled by log2e/8): st[mk][nq], lane = (k=mk*16+lg*4+r, q=nq*16+lr)
    f32x4 st[4][2] = {};
#pragma unroll
    for (int kk = 0; kk < 2; ++kk) {
      bf16x8 bk[4];
#pragma unroll
      for (int n = 0; n < 4; ++n) {
        int row = n * 16 + lr;
        int byteoff = (row * 128 + kk * 64 + lg * 16) ^ ((row & 7) << 4);
        bk[n] = *reinterpret_cast<const bf16x8*>((char*)Klds + byteoff);
      }
#pragma unroll
      for (int mk = 0; mk < 4; ++mk)
#pragma unroll
        for (int nq = 0; nq < 2; ++nq)
          st[mk][nq] = __builtin_amdgcn_mfma_f32_16x16x32_bf16(bk[mk], qf[nq][kk], st[mk][nq], 0, 0, 0);
    }

    // --- tile max per q-row (15 local fmax + 2 shfl) ---
    float tm[2];
#pragma unroll
    for (int nq = 0; nq < 2; ++nq) {
      float t0 = fmaxf(fmaxf(st[0][nq][0], st[0][nq][1]), fmaxf(st[0][nq][2], st[0][nq][3]));
      float t1 = fmaxf(fmaxf(st[1][nq][0], st[1][nq][1]), fmaxf(st[1][nq][2], st[1][nq][3]));
      float t2 = fmaxf(fmaxf(st[2][nq][0], st[2][nq][1]), fmaxf(st[2][nq][2], st[2][nq][3]));
      float t3 = fmaxf(fmaxf(st[3][nq][0], st[3][nq][1]), fmaxf(st[3][nq][2], st[3][nq][3]));
      float t = fmaxf(fmaxf(t0, t1), fmaxf(t2, t3));
      t = fmaxf(t, __shfl_xor(t, 16));
      t = fmaxf(t, __shfl_xor(t, 32));
      tm[nq] = t;
    }

    // --- defer-max (THR=8 in log2 domain: P <= 2^8) ---
    if (__any((tm[0] > mrun[0] + 8.f) || (tm[1] > mrun[1] + 8.f))) {
      float al[2];
#pragma unroll
      for (int nq = 0; nq < 2; ++nq) {
        float mn = fmaxf(mrun[nq], tm[nq]);
        al[nq] = __builtin_amdgcn_exp2f(mrun[nq] - mn);
        mrun[nq] = mn;
        lrun[nq] *= al[nq];
      }
#pragma unroll
      for (int m = 0; m < 2; ++m)
#pragma unroll
        for (int r = 0; r < 4; ++r) {
          float alv = __shfl(al[m], lg * 4 + r);      // o-row q=m*16+lg*4+r's factor lives at lane lg*4+r
#pragma unroll
          for (int n = 0; n < 4; ++n) o[m][n][r] *= alv;
        }
    }

    // --- P = exp2(S - m), row sum (15 local + 2 shfl) ---
#pragma unroll
    for (int mk = 0; mk < 4; ++mk)
#pragma unroll
      for (int nq = 0; nq < 2; ++nq)
#pragma unroll
        for (int r = 0; r < 4; ++r)
          st[mk][nq][r] = __builtin_amdgcn_exp2f(st[mk][nq][r] - mrun[nq]);
#pragma unroll
    for (int nq = 0; nq < 2; ++nq) {
      float s0 = (st[0][nq][0] + st[0][nq][1]) + (st[0][nq][2] + st[0][nq][3]);
      float s1 = (st[1][nq][0] + st[1][nq][1]) + (st[1][nq][2] + st[1][nq][3]);
      float s2 = (st[2][nq][0] + st[2][nq][1]) + (st[2][nq][2] + st[2][nq][3]);
      float s3 = (st[3][nq][0] + st[3][nq][1]) + (st[3][nq][2] + st[3][nq][3]);
      float rs = (s0 + s1) + (s2 + s3);
      rs += __shfl_xor(rs, 16);
      rs += __shfl_xor(rs, 32);
      lrun[nq] += rs;
    }

    // --- P^T(regs) -> P-layout LDS via cvt_pk pairs (k and k+1 contiguous: k=mk*16+lg*4+r)
    char* Pw = (char*)Plds[wid];
    {
      const int sw = (lr & 7) << 4;
#pragma unroll
      for (int nq = 0; nq < 2; ++nq) {
        int rowb = (nq * 16 + lr) * 128;
#pragma unroll
        for (int mk = 0; mk < 4; ++mk)
#pragma unroll
          for (int rp = 0; rp < 4; rp += 2) {
            int k = mk * 16 + lg * 4 + rp;
            uint32_t pk;
            asm("v_cvt_pk_bf16_f32 %0, %1, %2" : "=v"(pk) : "v"(st[mk][nq][rp]), "v"(st[mk][nq][rp + 1]));
            *(uint32_t*)(Pw + ((rowb + k * 2) ^ sw)) = pk;
          }
      }
    }
    asm volatile("s_waitcnt lgkmcnt(0)" ::: "memory");  // wave-private LDS: in-order DS + fence
    __builtin_amdgcn_sched_barrier(0);                  // rule #18: pin MFMA/ds_read below the wait

    // --- O += P V ---
#pragma unroll
    for (int kk = 0; kk < 2; ++kk) {
      bf16x8 pa[2], bv[4];
#pragma unroll
      for (int m = 0; m < 2; ++m) {
        int rowl = m * 16 + lr;
        int byteoff = (rowl * 128 + kk * 64 + lg * 16) ^ ((rowl & 7) << 4);
        pa[m] = *reinterpret_cast<const bf16x8*>(Pw + byteoff);
      }
#pragma unroll
      for (int n = 0; n < 4; ++n) {
        int d = n * 16 + lr;
        int byteoff = (d * 128 + kk * 64 + lg * 16) ^ ((d & 7) << 4);
        bv[n] = *reinterpret_cast<const bf16x8*>((char*)Vlds + byteoff);
      }
#pragma unroll
      for (int m = 0; m < 2; ++m)
#pragma unroll
        for (int n = 0; n < 4; ++n)
          o[m][n] = __builtin_amdgcn_mfma_f32_16x16x32_bf16(pa[m], bv[n], o[m][n], 0, 0, 0);
    }
  }

  // epilogue: fetch row-sums (lane lg*4+r holds q-row's lrun), normalize, store
  const int b = bh >> 4, h = bh & 15;
#pragma unroll
  for (int m = 0; m < 2; ++m)
#pragma unroll
    for (int r = 0; r < 4; ++r) {
      float lv = __shfl(lrun[m], lg * 4 + r);
      float inv = 1.0f / lv;
      int s = qt * 128 + wid * 32 + m * 16 + lg * 4 + r;
#pragma unroll
      for (int n = 0; n < 4; ++n) {
        int d = n * 16 + lr;
        Ob[(((size_t)b * S_LEN + s) * NHEAD + h) * HDIM + d] = f2bf(o[m][n][r] * inv);
      }
    }
}

// ---------- output projection -> fp32 d_out ----------
__global__ __launch_bounds__(256) void k_gemm_out(const u16* __restrict__ Aa, const u16* __restrict__ Wo,
                                                  float* __restrict__ out) {
  __shared__ __align__(16) u16 As[128 * 32];
  __shared__ __align__(16) u16 Bs[128 * 32];
  f32x4 acc[4][4] = {};
  const int brow = blockIdx.x * 128, bcol = blockIdx.y * 128;
  gemm_ml(Aa, Wo, brow, bcol, As, Bs, acc);

  const int tid = threadIdx.x, wid = tid >> 6, lane = tid & 63;
  const int lr = lane & 15, lg = lane >> 4;
  const int wr = wid >> 1, wc = wid & 1;
#pragma unroll
  for (int m = 0; m < 4; ++m)
#pragma unroll
    for (int n = 0; n < 4; ++n)
#pragma unroll
      for (int r = 0; r < 4; ++r) {
        int grow = brow + wr * 64 + m * 16 + lg * 4 + r;
        int gcol = bcol + wc * 64 + n * 16 + lr;
        out[(size_t)grow * HID + gcol] = acc[m][n][r];
      }
}

// ---------- launcher ----------
extern "C" void kernel_launch(void* const* d_in, const int* in_sizes, int n_in,
                              void* d_out, int out_size, void* d_ws, size_t ws_size,
                              hipStream_t stream) {
  const float* hs = (const float*)d_in[0];
  const float* Wq = (const float*)d_in[1];
  const float* Wk = (const float*)d_in[2];
  const float* Wv = (const float*)d_in[3];
  const float* Wo = (const float*)d_in[4];

  char* ws = (char*)d_ws;
  u16* Xbf  = (u16*)(ws);                                   // 8192x1024      (16 MB)
  u16* Wqkv = (u16*)(ws + 16777216);                        // 3072x1024      ( 6 MB)
  u16* Wobf = (u16*)(ws + 23068672);                        // 1024x1024      ( 2 MB)
  u16* Qb   = (u16*)(ws + 25165824);                        // [B,NH,S,HD]    (16 MB)
  u16* Kb   = (u16*)(ws + 41943040);                        // [B,NH,S,HD]    (16 MB)
  u16* Vb   = (u16*)(ws + 58720256);                        // [B,NH,S,HD]    (16 MB)
  u16* AO   = (u16*)(ws + 75497472);                        // [B,S,NH,HD]    (16 MB) -> total 92274688 B
  u16* Vt   = Xbf;                                          // [B,NH,HD,S]: reuse Xbf (dead after k_gemm_qkv)

  k_cvt<<<2048, 256, 0, stream>>>(hs, Xbf, (MROWS * HID) / 4);
  k_cvtw<<<4096, 256, 0, stream>>>(Wq, Wk, Wv, Wo, Wqkv, Wobf);

  k_gemm_qkv<<<dim3(MROWS / 128, 3072 / 128), 256, 0, stream>>>(Xbf, Wqkv, Qb, Kb, Vb);
  k_vt<<<dim3(S_LEN / 64, 4 * NHEAD), 256, 0, stream>>>(Vb, Vt);
  k_attn<<<dim3(S_LEN / 128, 4 * NHEAD), 256, 0, stream>>>(Qb, Kb, Vt, AO);
  k_gemm_out<<<dim3(MROWS / 128, HID / 128), 256, 0, stream>>>(AO, Wobf, (float*)d_out);
}